// Round 2
// baseline (197.759 us; speedup 1.0000x reference)
//
#include <hip/hip_runtime.h>
#include <cmath>

// 2-state HMM filtering scan, parallelized over time via associative
// 2x2 matrix-product scan (state is projectively linear in the evidence
// matrices M_t = diag(e_t) @ T).
//
// Layout: one wave (64 lanes) per session; lane owns LCH=32 consecutive
// trials. Phase 1: per-lane chunk product (normalized per step) + register
// cache of per-trial evidence. Phase 2: Kogge-Stone wave scan of 2x2
// products (order-preserving). Phase 3: replay chunk from its start state,
// identical arithmetic to the reference step, float4-packed stores.

constexpr int NSESS = 4096;
constexpr int NTRIALS = 2048;
constexpr int LCH = 32;              // trials per lane; 64 lanes * 32 = 2048
constexpr int WAVES_PER_BLOCK = 4;   // 256-thread blocks, 4 sessions each

__global__ __launch_bounds__(256) void hmm_scan_kernel(
    const float* __restrict__ inp,     // (NSESS, NTRIALS, 3)
    const float* __restrict__ p_raw,   // (1,)
    const float* __restrict__ c_raw,   // (1,)
    float* __restrict__ out)           // (NSESS, NTRIALS, 2)
{
    const int lane = threadIdx.x & 63;
    const int wid  = threadIdx.x >> 6;
    const int sess = blockIdx.x * WAVES_PER_BLOCK + wid;
    if (sess >= NSESS) return;

    const float p = 1.0f / (1.0f + __expf(-p_raw[0]));
    const float c = 1.0f / (1.0f + __expf(-c_raw[0]));
    const float A = 0.5f * (1.0f + c), B = 0.5f * (1.0f - c);
    const float q = 0.5f * (1.0f + p), r = 0.5f * (1.0f - p);

    // ---- Phase 1: per-lane chunk product + evidence register cache ----
    const float* x = inp + ((size_t)sess * NTRIALS + (size_t)lane * LCH) * 3;
    const float4* xv = reinterpret_cast<const float4*>(x);  // 16B-aligned: lane*384B

    float e0c[LCH], e1c[LCH];
    float p00 = 1.f, p01 = 0.f, p10 = 0.f, p11 = 1.f;

    #pragma unroll
    for (int g = 0; g < LCH / 4; ++g) {
        float4 v0 = xv[3 * g + 0];
        float4 v1 = xv[3 * g + 1];
        float4 v2 = xv[3 * g + 2];
        float t[4][3] = {{v0.x, v0.y, v0.z}, {v0.w, v1.x, v1.y},
                         {v1.z, v1.w, v2.x}, {v2.y, v2.z, v2.w}};
        #pragma unroll
        for (int j = 0; j < 4; ++j) {
            float cl = t[j][0], cr = t[j][1], o = t[j][2];
            float s0 = cl * o, s1 = cl - s0, s2 = cr * o, s3 = cr - s2;
            float d0 = s0 + s3, d1 = s1 + s2;
            float e0 = d0 * A + d1 * B;
            float e1 = d0 * B + d1 * A;
            e0c[4 * g + j] = e0;
            e1c[4 * g + j] = e1;
            // M_t = diag(e) @ T; reference's like_sum==0 branch => M_t = T
            float m00, m01, m10, m11;
            if (e0 == 0.f && e1 == 0.f) { m00 = q; m01 = r; m10 = r; m11 = q; }
            else { m00 = e0 * q; m01 = e0 * r; m10 = e1 * r; m11 = e1 * q; }
            float n00 = p00 * m00 + p01 * m10;
            float n01 = p00 * m01 + p01 * m11;
            float n10 = p10 * m00 + p11 * m10;
            float n11 = p10 * m01 + p11 * m11;
            float inv = 1.f / (n00 + n01 + n10 + n11);  // renorm: avoid underflow
            p00 = n00 * inv; p01 = n01 * inv; p10 = n10 * inv; p11 = n11 * inv;
        }
    }

    // ---- Phase 2: Kogge-Stone inclusive scan of 2x2 products over wave ----
    // C_i = P_0 @ P_1 @ ... @ P_i  (earlier matrices on the LEFT)
    #pragma unroll
    for (int d = 1; d < 64; d <<= 1) {
        float a00 = __shfl_up(p00, d);
        float a01 = __shfl_up(p01, d);
        float a10 = __shfl_up(p10, d);
        float a11 = __shfl_up(p11, d);
        if (lane >= d) {
            float n00 = a00 * p00 + a01 * p10;
            float n01 = a00 * p01 + a01 * p11;
            float n10 = a10 * p00 + a11 * p10;
            float n11 = a10 * p01 + a11 * p11;
            float inv = 1.f / (n00 + n01 + n10 + n11);
            p00 = n00 * inv; p01 = n01 * inv; p10 = n10 * inv; p11 = n11 * inv;
        }
    }

    // Exclusive prefix -> start state for this lane's chunk
    float c00 = __shfl_up(p00, 1);
    float c01 = __shfl_up(p01, 1);
    float c10 = __shfl_up(p10, 1);
    float c11 = __shfl_up(p11, 1);
    float st0 = 0.5f, st1 = 0.5f;
    if (lane > 0) {
        float v0 = 0.5f * c00 + 0.5f * c10;
        float v1 = 0.5f * c01 + 0.5f * c11;
        float inv = 1.f / (v0 + v1);
        st0 = v0 * inv; st1 = v1 * inv;
    }

    // ---- Phase 3: replay chunk exactly like the reference step ----
    float4* yv = reinterpret_cast<float4*>(
        out + ((size_t)sess * NTRIALS + (size_t)lane * LCH) * 2);

    #pragma unroll
    for (int i = 0; i < LCH; i += 2) {
        float a0, a1, b0, b1;
        {
            float l0 = st0 * e0c[i], l1 = st1 * e1c[i];
            float ls = l0 + l1;
            if (ls == 0.f) { l0 = st0; l1 = st1; ls = 1.f; }
            float inv = 1.f / ls;
            float n0 = l0 * inv, n1 = l1 * inv;
            st0 = n0 * q + n1 * r;
            st1 = n0 * r + n1 * q;
            a0 = st0; a1 = st1;
        }
        {
            float l0 = st0 * e0c[i + 1], l1 = st1 * e1c[i + 1];
            float ls = l0 + l1;
            if (ls == 0.f) { l0 = st0; l1 = st1; ls = 1.f; }
            float inv = 1.f / ls;
            float n0 = l0 * inv, n1 = l1 * inv;
            st0 = n0 * q + n1 * r;
            st1 = n0 * r + n1 * q;
            b0 = st0; b1 = st1;
        }
        yv[i >> 1] = make_float4(a0, a1, b0, b1);
    }
}

extern "C" void kernel_launch(void* const* d_in, const int* in_sizes, int n_in,
                              void* d_out, int out_size, void* d_ws, size_t ws_size,
                              hipStream_t stream) {
    const float* inp   = (const float*)d_in[0];
    const float* p_raw = (const float*)d_in[1];
    const float* c_raw = (const float*)d_in[2];
    float* out = (float*)d_out;

    dim3 grid(NSESS / WAVES_PER_BLOCK);   // 1024 blocks
    dim3 block(64 * WAVES_PER_BLOCK);     // 256 threads = 4 waves = 4 sessions
    hmm_scan_kernel<<<grid, block, 0, stream>>>(inp, p_raw, c_raw, out);
}

// Round 4
// 166.880 us; speedup vs baseline: 1.1850x; 1.1850x over previous
//
#include <hip/hip_runtime.h>
#include <cmath>

// 2-state HMM filtering scan. Block = 1 session (4 waves, 256 threads);
// lane owns 8 consecutive trials. Time-parallel via associative 2x2
// matrix-product scan: M_t = diag(e_t) @ T, state_t = normalize(s0 @ M_1..M_t).
//
// Chunk products are NOT renormalized per step (entries >= ~3e-12, safe in
// f32); renorm happens only at scan combines. Replay keeps an unnormalized
// state; the output-normalizing rcp is off the recurrence's critical path.
// Input/output staged through LDS for fully coalesced global traffic.

constexpr int NSESS   = 4096;
constexpr int NTRIALS = 2048;
constexpr int WAVES   = 4;                    // waves per block = per session
constexpr int THREADS = WAVES * 64;           // 256
constexpr int TPW     = NTRIALS / WAVES;      // 512 trials per wave
constexpr int LCH     = TPW / 64;             // 8 trials per lane
constexpr int IN_F4   = NTRIALS * 3 / 4;      // 1536 float4 input per block
constexpr int OUT_F4  = NTRIALS * 2 / 4;      // 1024 float4 output per block

__global__ __launch_bounds__(THREADS) void hmm_kernel(
    const float* __restrict__ inp,     // (NSESS, NTRIALS, 3)
    const float* __restrict__ p_raw,
    const float* __restrict__ c_raw,
    float* __restrict__ out)           // (NSESS, NTRIALS, 2)
{
    __shared__ float4 lds[IN_F4];          // 24 KB; reused for output staging
    __shared__ float  lds_tot[WAVES][4];   // per-wave 2x2 totals

    const int t    = threadIdx.x;
    const int lane = t & 63;
    const int w    = t >> 6;
    const int sess = blockIdx.x;

    const float p = 1.0f / (1.0f + __expf(-p_raw[0]));
    const float c = 1.0f / (1.0f + __expf(-c_raw[0]));
    const float A = 0.5f * (1.0f + c), B = 0.5f * (1.0f - c);
    const float q = 0.5f * (1.0f + p), r = 0.5f * (1.0f - p);

    // ---- Stage input: global -> LDS, fully coalesced ----
    const float4* g_in = reinterpret_cast<const float4*>(inp) + (size_t)sess * IN_F4;
    #pragma unroll
    for (int k = 0; k < IN_F4 / THREADS; ++k)        // 6 float4 per thread
        lds[k * THREADS + t] = g_in[k * THREADS + t];
    __syncthreads();

    // ---- Phase 1: evidence (registers) + un-renormalized chunk product ----
    float e0c[LCH], e1c[LCH];
    float p00 = 1.f, p01 = 0.f, p10 = 0.f, p11 = 1.f;
    {
        float4 v[LCH * 3 / 4];                        // 6 float4 = 8 trials
        const int base = w * (TPW * 3 / 4) + lane * (LCH * 3 / 4);
        #pragma unroll
        for (int k = 0; k < LCH * 3 / 4; ++k) v[k] = lds[base + k];
        const float* f = reinterpret_cast<const float*>(v);
        #pragma unroll
        for (int i = 0; i < LCH; ++i) {
            float cl = f[3 * i], cr = f[3 * i + 1], o = f[3 * i + 2];
            float d0 = cl * o + cr * (1.f - o);
            float d1 = cl * (1.f - o) + cr * o;
            float e0 = d0 * A + d1 * B;
            float e1 = d0 * B + d1 * A;
            e0c[i] = e0; e1c[i] = e1;
            float m00, m01, m10, m11;
            if (e0 == 0.f && e1 == 0.f) { m00 = q; m01 = r; m10 = r; m11 = q; }
            else { m00 = e0 * q; m01 = e0 * r; m10 = e1 * r; m11 = e1 * q; }
            float n00 = p00 * m00 + p01 * m10;
            float n01 = p00 * m01 + p01 * m11;
            float n10 = p10 * m00 + p11 * m10;
            float n11 = p10 * m01 + p11 * m11;
            p00 = n00; p01 = n01; p10 = n10; p11 = n11;
        }
    }

    // ---- Phase 2: wave Kogge-Stone scan of 2x2 products (renorm/combine) ----
    #pragma unroll
    for (int d = 1; d < 64; d <<= 1) {
        float a00 = __shfl_up(p00, d);
        float a01 = __shfl_up(p01, d);
        float a10 = __shfl_up(p10, d);
        float a11 = __shfl_up(p11, d);
        if (lane >= d) {
            float n00 = a00 * p00 + a01 * p10;
            float n01 = a00 * p01 + a01 * p11;
            float n10 = a10 * p00 + a11 * p10;
            float n11 = a10 * p01 + a11 * p11;
            float inv = 1.f / (n00 + n01 + n10 + n11);
            p00 = n00 * inv; p01 = n01 * inv; p10 = n10 * inv; p11 = n11 * inv;
        }
    }

    // Wave totals -> LDS (lane 63 holds the inclusive total)
    if (lane == 63) {
        lds_tot[w][0] = p00; lds_tot[w][1] = p01;
        lds_tot[w][2] = p10; lds_tot[w][3] = p11;
    }
    __syncthreads();   // also fences: all LDS-input reads done before reuse

    // ---- Phase 3: start state = ([.5,.5] @ prefix-waves) @ C_{lane-1} ----
    float v0 = 0.5f, v1 = 0.5f;
    for (int ww = 0; ww < w; ++ww) {                  // wave-uniform bound
        float t00 = lds_tot[ww][0], t01 = lds_tot[ww][1];
        float t10 = lds_tot[ww][2], t11 = lds_tot[ww][3];
        float n0 = v0 * t00 + v1 * t10;
        float n1 = v0 * t01 + v1 * t11;
        float inv = 1.f / (n0 + n1);
        v0 = n0 * inv; v1 = n1 * inv;
    }
    float c00 = __shfl_up(p00, 1);
    float c01 = __shfl_up(p01, 1);
    float c10 = __shfl_up(p10, 1);
    float c11 = __shfl_up(p11, 1);
    float u0 = v0, u1 = v1;
    if (lane > 0) {
        float n0 = v0 * c00 + v1 * c10;
        float n1 = v0 * c01 + v1 * c11;
        float inv = 1.f / (n0 + n1);
        u0 = n0 * inv; u1 = n1 * inv;
    }

    // ---- Phase 4: replay 8 trials; outputs to LDS (transposed layout) ----
    // Unnormalized recurrence u' = (u .* e) @ T; normalize only for output.
    float4* lds_out = lds;                            // reuse (16 KB of 24)
    #pragma unroll
    for (int i = 0; i < LCH; i += 2) {
        float a0, a1, b0, b1;
        {
            float w0 = u0 * e0c[i], w1 = u1 * e1c[i];
            if (w0 + w1 == 0.f) { w0 = u0; w1 = u1; }   // ref zero-guard
            float n0 = w0 * q + w1 * r;
            float n1 = w0 * r + w1 * q;
            float inv = 1.f / (n0 + n1);                // off recurrence chain
            a0 = n0 * inv; a1 = n1 * inv;
            u0 = n0; u1 = n1;
        }
        {
            float w0 = u0 * e0c[i + 1], w1 = u1 * e1c[i + 1];
            if (w0 + w1 == 0.f) { w0 = u0; w1 = u1; }
            float n0 = w0 * q + w1 * r;
            float n1 = w0 * r + w1 * q;
            float inv = 1.f / (n0 + n1);
            b0 = n0 * inv; b1 = n1 * inv;
            u0 = n0; u1 = n1;
        }
        // wave region w: addr = w*256 + i4*64 + lane  (i4 = i/2 in [0,4))
        lds_out[w * 256 + (i >> 1) * 64 + lane] = make_float4(a0, a1, b0, b1);
    }
    __syncthreads();

    // ---- Stage output: LDS -> global, fully coalesced ----
    float4* g_out = reinterpret_cast<float4*>(out) + (size_t)sess * OUT_F4;
    #pragma unroll
    for (int k = 0; k < OUT_F4 / THREADS; ++k) {      // 4 float4 per thread
        // global float4 j = k*256 + t  ->  lds addr = k*256 + (t&3)*64 + (t>>2)
        g_out[k * 256 + t] = lds_out[k * 256 + (t & 3) * 64 + (t >> 2)];
    }
}

extern "C" void kernel_launch(void* const* d_in, const int* in_sizes, int n_in,
                              void* d_out, int out_size, void* d_ws, size_t ws_size,
                              hipStream_t stream) {
    const float* inp   = (const float*)d_in[0];
    const float* p_raw = (const float*)d_in[1];
    const float* c_raw = (const float*)d_in[2];
    float* out = (float*)d_out;

    hmm_kernel<<<dim3(NSESS), dim3(THREADS), 0, stream>>>(inp, p_raw, c_raw, out);
}